// Round 2
// baseline (1056.464 us; speedup 1.0000x reference)
//
#include <hip/hip_runtime.h>
#include <cmath>

#define B_   4
#define L_   1024
#define H_   768
#define NH_  12
#define NE_  30
#define M_   6
#define P_   600
#define EMB_ 768
#define BS_  16
#define NC_  97

// ---------------- entity logsumexp pooling: e_emb[b,e,h] ----------------
__global__ __launch_bounds__(256) void k_entity_pool(
    const float* __restrict__ seq, const float* __restrict__ mmask,
    const int* __restrict__ midx, float* __restrict__ e_emb)
{
  int be = blockIdx.x;                // b*NE+e
  int tid = threadIdx.x;
  int idx[M_]; float msk[M_];
#pragma unroll
  for (int m = 0; m < M_; ++m) {
    idx[m] = midx[be * M_ + m];
    msk[m] = mmask[be * M_ + m];
  }
  int b = be / NE_;
  const float* sb = seq + (size_t)b * L_ * H_;
  for (int h = tid; h < H_; h += 256) {
    float v[M_]; float mx = -3.0e38f;
#pragma unroll
    for (int m = 0; m < M_; ++m) {
      float x = (msk[m] > 0.f) ? sb[(size_t)idx[m] * H_ + h] : -1e30f;
      v[m] = x; mx = fmaxf(mx, x);
    }
    float s = 0.f;
#pragma unroll
    for (int m = 0; m < M_; ++m) s += expf(v[m] - mx);
    e_emb[(size_t)be * H_ + h] = mx + logf(s);
  }
}

// ---------------- entity attention mean: e_att[b,e,nh,l] ----------------
__global__ __launch_bounds__(256) void k_entity_att(
    const float* __restrict__ att, const float* __restrict__ mmask,
    const int* __restrict__ midx, float* __restrict__ e_att)
{
  int i = blockIdx.x * 256 + threadIdx.x;    // over B*NE*NH*L
  if (i >= B_*NE_*NH_*L_) return;
  int l  = i & (L_ - 1);
  int nh = (i >> 10) % NH_;
  int be = i / (L_ * NH_);
  int b  = be / NE_;
  float s = 0.f, cnt = 0.f;
#pragma unroll
  for (int m = 0; m < M_; ++m) {
    float mk = mmask[be*M_ + m];
    cnt += mk;
    int id = midx[be*M_ + m];
    s += mk * att[(((size_t)b*NH_ + nh)*L_ + id)*L_ + l];
  }
  e_att[i] = s / fmaxf(cnt, 1.f);
}

// ---------------- ht_att[b,p,l] (normalized) ----------------
__global__ __launch_bounds__(256) void k_htatt(
    const float* __restrict__ e_att, const int* __restrict__ hts,
    float* __restrict__ htatt)
{
  int bp = blockIdx.x;                 // b*P+p
  int b = bp / P_;
  int tid = threadIdx.x;
  int hi = hts[bp*2 + 0], ti = hts[bp*2 + 1];
  const float* ha = e_att + (size_t)(b*NE_ + hi) * NH_ * L_;
  const float* ta = e_att + (size_t)(b*NE_ + ti) * NH_ * L_;
  float vals[4]; float loc = 0.f;
#pragma unroll
  for (int q = 0; q < 4; ++q) {
    int l = tid + q*256;
    float s = 0.f;
#pragma unroll
    for (int nh = 0; nh < NH_; ++nh) s += ha[nh*L_ + l] * ta[nh*L_ + l];
    s *= (1.f / NH_);
    vals[q] = s; loc += s;
  }
  __shared__ float red[4];
  for (int off = 32; off > 0; off >>= 1) loc += __shfl_down(loc, off, 64);
  if ((tid & 63) == 0) red[tid >> 6] = loc;
  __syncthreads();
  float inv = 1.f / (red[0] + red[1] + red[2] + red[3] + 1e-30f);
  float* o = htatt + (size_t)bp * L_;
#pragma unroll
  for (int q = 0; q < 4; ++q) o[tid + q*256] = vals[q] * inv;
}

// ---------------- rs[b,p,h] = ht_att @ seq  (64x64 tile fp32 GEMM) ----------------
__global__ __launch_bounds__(256) void k_rs(
    const float* __restrict__ htatt, const float* __restrict__ seq,
    float* __restrict__ rs)
{
  int b  = blockIdx.z;
  int p0 = blockIdx.y * 64;
  int h0 = blockIdx.x * 64;
  int tid = threadIdx.x;
  __shared__ float As[16][68];
  __shared__ float Bs[16][68];
  int tx = tid & 15, ty = tid >> 4;
  float acc[4][4] = {};
  const float* Ab = htatt + ((size_t)b*P_ + p0) * L_;
  const float* Bb = seq + (size_t)b*L_*H_ + h0;
  int skk = tid & 15, srr = tid >> 4;       // A-stage map
  int bkk = tid >> 6, bhc = tid & 63;       // B-stage map
  for (int l0 = 0; l0 < L_; l0 += 16) {
#pragma unroll
    for (int pass = 0; pass < 4; ++pass) {
      int r = srr + pass*16;
      As[skk][r] = (p0 + r < P_) ? Ab[(size_t)r*L_ + l0 + skk] : 0.f;
      int kk = bkk + pass*4;
      Bs[kk][bhc] = Bb[(size_t)(l0+kk)*H_ + bhc];
    }
    __syncthreads();
#pragma unroll
    for (int kk = 0; kk < 16; ++kk) {
      float a[4], bv[4];
#pragma unroll
      for (int i = 0; i < 4; ++i) a[i] = As[kk][ty*4 + i];
#pragma unroll
      for (int j = 0; j < 4; ++j) bv[j] = Bs[kk][tx*4 + j];
#pragma unroll
      for (int i = 0; i < 4; ++i)
#pragma unroll
        for (int j = 0; j < 4; ++j) acc[i][j] += a[i] * bv[j];
    }
    __syncthreads();
  }
#pragma unroll
  for (int i = 0; i < 4; ++i) {
    int p = p0 + ty*4 + i;
    if (p < P_) {
      float* o = rs + (size_t)(b*P_ + p)*H_ + h0 + tx*4;
#pragma unroll
      for (int j = 0; j < 4; ++j) o[j] = acc[i][j];
    }
  }
}

// ---------------- per-entity extractor half: pre[b,e,o] = e_emb . W[:, :H] ----------------
__global__ __launch_bounds__(256) void k_entity_pre(
    const float* __restrict__ e_emb, const float* __restrict__ headW,
    const float* __restrict__ tailW, float* __restrict__ hpre,
    float* __restrict__ tpre)
{
  int be = blockIdx.x;
  int sel = blockIdx.y;
  const float* W = sel ? tailW : headW;
  float* out = (sel ? tpre : hpre) + (size_t)be * EMB_;
  __shared__ float emb[H_];
  int tid = threadIdx.x;
  for (int h = tid; h < H_; h += 256) emb[h] = e_emb[(size_t)be*H_ + h];
  __syncthreads();
  for (int o = tid; o < EMB_; o += 256) {
    const float* wr = W + (size_t)o * (2*H_);
    float acc = 0.f;
    for (int d = 0; d < H_; d += 4) {
      float4 u = *reinterpret_cast<const float4*>(wr + d);
      acc += emb[d+0]*u.x + emb[d+1]*u.y + emb[d+2]*u.z + emb[d+3]*u.w;
    }
    out[o] = acc;
  }
}

// ---------------- per-pair extractor: hs/ts = tanh(pre + rs.W[:,H:] + b) ----------------
__global__ __launch_bounds__(256) void k_extract(
    const float* __restrict__ rs, const float* __restrict__ headW,
    const float* __restrict__ tailW, const float* __restrict__ headb,
    const float* __restrict__ tailb, const float* __restrict__ hpre,
    const float* __restrict__ tpre, const int* __restrict__ hts,
    float* __restrict__ hs, float* __restrict__ ts)
{
  int sel = blockIdx.z;
  const float* W = sel ? tailW : headW;
  const float* bias = sel ? tailb : headb;
  const float* pre = sel ? tpre : hpre;
  float* out = sel ? ts : hs;
  int r0 = blockIdx.y * 64;
  int o0 = blockIdx.x * 64;
  int tid = threadIdx.x;
  __shared__ float As[16][68];
  __shared__ float Bs[16][68];
  int tx = tid & 15, ty = tid >> 4;
  float acc[4][4] = {};
  int skk = tid & 15, srr = tid >> 4;
  for (int k0 = 0; k0 < H_; k0 += 16) {
#pragma unroll
    for (int pass = 0; pass < 4; ++pass) {
      int r = srr + pass*16;
      int row = r0 + r;
      As[skk][r] = (row < B_*P_) ? rs[(size_t)row*H_ + k0 + skk] : 0.f;
      int oc = srr + pass*16;
      Bs[skk][oc] = W[(size_t)(o0+oc)*(2*H_) + H_ + k0 + skk];
    }
    __syncthreads();
#pragma unroll
    for (int kk = 0; kk < 16; ++kk) {
      float a[4], bv[4];
#pragma unroll
      for (int i = 0; i < 4; ++i) a[i] = As[kk][ty*4 + i];
#pragma unroll
      for (int j = 0; j < 4; ++j) bv[j] = Bs[kk][tx*4 + j];
#pragma unroll
      for (int i = 0; i < 4; ++i)
#pragma unroll
        for (int j = 0; j < 4; ++j) acc[i][j] += a[i] * bv[j];
    }
    __syncthreads();
  }
#pragma unroll
  for (int i = 0; i < 4; ++i) {
    int row = r0 + ty*4 + i;
    if (row < B_*P_) {
      int b = row / P_;
      int e = hts[row*2 + sel];
      const float* prow = pre + (size_t)(b*NE_ + e) * EMB_;
      float* orow = out + (size_t)row * EMB_;
#pragma unroll
      for (int j = 0; j < 4; ++j) {
        int o = o0 + tx*4 + j;
        orow[o] = tanhf(acc[i][j] + prow[o] + bias[o]);
      }
    }
  }
}

// ---------------- Wc[d, c] = sum_h projW[h,d] * clsW[c,h]  (stored [12288][128]) -----
__global__ __launch_bounds__(256) void k_wc(
    const float* __restrict__ projW, const float* __restrict__ clsW,
    float* __restrict__ Wc)
{
  int d0 = blockIdx.y * 64;
  int c0 = blockIdx.x * 64;
  int tid = threadIdx.x;
  __shared__ float As[16][68];
  __shared__ float Bs[16][68];
  int tx = tid & 15, ty = tid >> 4;
  float acc[4][4] = {};
  int admn = tid & 63, akk = tid >> 6;
  int bkk = tid & 15, bcnb = tid >> 4;
  for (int k0 = 0; k0 < H_; k0 += 16) {
#pragma unroll
    for (int pass = 0; pass < 4; ++pass) {
      int kk = akk + pass*4;
      As[kk][admn] = projW[(size_t)(k0+kk)*(EMB_*BS_) + d0 + admn];
      int cn = bcnb + pass*16;
      int c = c0 + cn;
      Bs[bkk][cn] = (c < NC_) ? clsW[(size_t)c*H_ + k0 + bkk] : 0.f;
    }
    __syncthreads();
#pragma unroll
    for (int kk = 0; kk < 16; ++kk) {
      float a[4], bv[4];
#pragma unroll
      for (int i = 0; i < 4; ++i) a[i] = As[kk][ty*4 + i];
#pragma unroll
      for (int j = 0; j < 4; ++j) bv[j] = Bs[kk][tx*4 + j];
#pragma unroll
      for (int i = 0; i < 4; ++i)
#pragma unroll
        for (int j = 0; j < 4; ++j) acc[i][j] += a[i] * bv[j];
    }
    __syncthreads();
  }
#pragma unroll
  for (int i = 0; i < 4; ++i) {
    int d = d0 + ty*4 + i;
#pragma unroll
    for (int j = 0; j < 4; ++j) {
      int c = c0 + tx*4 + j;
      Wc[(size_t)d*128 + c] = (c < NC_) ? acc[i][j] : 0.f;
    }
  }
}

// ---------------- logits: bl(hs,ts) @ Wc + cls_b, bl generated on the fly ------------
__global__ __launch_bounds__(256) void k_logits(
    const float* __restrict__ hs, const float* __restrict__ ts,
    const float* __restrict__ Wc, const float* __restrict__ clsb,
    float* __restrict__ out)
{
  int r0 = blockIdx.x * 8;           // 8 pair-rows per block, 300 blocks
  int tid = threadIdx.x;
  int c = tid & 127;
  int g = tid >> 7;                  // 0/1 -> rows g*4 .. g*4+3
  __shared__ float hs_s[8][17];
  __shared__ float ts_s[8][17];
  float acc[4] = {0.f, 0.f, 0.f, 0.f};
  int lp = (tid & 127) >> 4, lj = tid & 15;
  for (int k = 0; k < 48; ++k) {
    __syncthreads();
    if (tid < 128) hs_s[lp][lj] = hs[(size_t)(r0 + lp)*EMB_ + k*16 + lj];
    else           ts_s[lp][lj] = ts[(size_t)(r0 + lp)*EMB_ + k*16 + lj];
    __syncthreads();
    float tv[4][16];
#pragma unroll
    for (int r = 0; r < 4; ++r)
#pragma unroll
      for (int jj = 0; jj < 16; ++jj) tv[r][jj] = ts_s[g*4 + r][jj];
    const float* wbase = Wc + (size_t)k*256*128 + c;
#pragma unroll
    for (int i = 0; i < 16; ++i) {
      float a0 = hs_s[g*4+0][i], a1 = hs_s[g*4+1][i];
      float a2 = hs_s[g*4+2][i], a3 = hs_s[g*4+3][i];
#pragma unroll
      for (int jj = 0; jj < 16; ++jj) {
        float w = wbase[(i*16 + jj)*128];
        acc[0] += a0 * tv[0][jj] * w;
        acc[1] += a1 * tv[1][jj] * w;
        acc[2] += a2 * tv[2][jj] * w;
        acc[3] += a3 * tv[3][jj] * w;
      }
    }
  }
  if (c < NC_) {
    float cb = clsb[c];
#pragma unroll
    for (int r = 0; r < 4; ++r) {
      int row = r0 + g*4 + r;
      out[(size_t)row*NC_ + c] = acc[r] + cb;
    }
  }
}

extern "C" void kernel_launch(void* const* d_in, const int* in_sizes, int n_in,
                              void* d_out, int out_size, void* d_ws, size_t ws_size,
                              hipStream_t stream) {
  const float* seq   = (const float*)d_in[0];
  const float* att   = (const float*)d_in[1];
  const float* headW = (const float*)d_in[2];
  const float* headb = (const float*)d_in[3];
  const float* tailW = (const float*)d_in[4];
  const float* tailb = (const float*)d_in[5];
  const float* projW = (const float*)d_in[6];
  const float* clsW  = (const float*)d_in[7];
  const float* clsb  = (const float*)d_in[8];
  const float* mmask = (const float*)d_in[9];
  const int* midx = (const int*)d_in[10];
  const int* hts  = (const int*)d_in[11];

  float* w = (float*)d_ws;
  float* e_emb = w;  w += (size_t)B_*NE_*H_;
  float* e_att = w;  w += (size_t)B_*NE_*NH_*L_;
  float* htatt = w;  w += (size_t)B_*P_*L_;
  float* rs    = w;  w += (size_t)B_*P_*H_;
  float* hpre  = w;  w += (size_t)B_*NE_*EMB_;
  float* tpre  = w;  w += (size_t)B_*NE_*EMB_;
  float* hsb   = w;  w += (size_t)B_*P_*EMB_;
  float* tsb   = w;  w += (size_t)B_*P_*EMB_;
  float* Wc    = w;  w += (size_t)EMB_*BS_*128;

  k_entity_pool<<<B_*NE_, 256, 0, stream>>>(seq, mmask, midx, e_emb);
  k_entity_att<<<(B_*NE_*NH_*L_)/256, 256, 0, stream>>>(att, mmask, midx, e_att);
  k_wc<<<dim3(2, 192), 256, 0, stream>>>(projW, clsW, Wc);
  k_htatt<<<B_*P_, 256, 0, stream>>>(e_att, hts, htatt);
  k_rs<<<dim3(12, 10, 4), 256, 0, stream>>>(htatt, seq, rs);
  k_entity_pre<<<dim3(B_*NE_, 2), 256, 0, stream>>>(e_emb, headW, tailW, hpre, tpre);
  k_extract<<<dim3(12, 38, 2), 256, 0, stream>>>(rs, headW, tailW, headb, tailb,
                                                 hpre, tpre, hts, hsb, tsb);
  k_logits<<<300, 256, 0, stream>>>(hsb, tsb, Wc, clsb, (float*)d_out);
}

// Round 3
// 538.063 us; speedup vs baseline: 1.9635x; 1.9635x over previous
//
#include <hip/hip_runtime.h>
#include <cmath>

#define B_   4
#define L_   1024
#define H_   768
#define NH_  12
#define NE_  30
#define M_   6
#define P_   600
#define EMB_ 768
#define BS_  16
#define NC_  97

typedef __bf16 bf16x8 __attribute__((ext_vector_type(8)));
typedef float floatx4 __attribute__((ext_vector_type(4)));

union V16 { uint4 q; __bf16 b[8]; bf16x8 v; };

// =================== small pre/post kernels ===================

__global__ __launch_bounds__(256) void k_entity_pool(
    const float* __restrict__ seq, const float* __restrict__ mmask,
    const int* __restrict__ midx, float* __restrict__ e_emb)
{
  int be = blockIdx.x;
  int tid = threadIdx.x;
  int idx[M_]; float msk[M_];
#pragma unroll
  for (int m = 0; m < M_; ++m) {
    idx[m] = midx[be * M_ + m];
    msk[m] = mmask[be * M_ + m];
  }
  int b = be / NE_;
  const float* sb = seq + (size_t)b * L_ * H_;
  for (int h = tid; h < H_; h += 256) {
    float v[M_]; float mx = -3.0e38f;
#pragma unroll
    for (int m = 0; m < M_; ++m) {
      float x = (msk[m] > 0.f) ? sb[(size_t)idx[m] * H_ + h] : -1e30f;
      v[m] = x; mx = fmaxf(mx, x);
    }
    float s = 0.f;
#pragma unroll
    for (int m = 0; m < M_; ++m) s += expf(v[m] - mx);
    e_emb[(size_t)be * H_ + h] = mx + logf(s);
  }
}

__global__ __launch_bounds__(256) void k_entity_att(
    const float* __restrict__ att, const float* __restrict__ mmask,
    const int* __restrict__ midx, float* __restrict__ e_att)
{
  int i = blockIdx.x * 256 + threadIdx.x;
  if (i >= B_*NE_*NH_*L_) return;
  int be = i / (L_ * NH_);
  int b  = be / NE_;
  int nh = (i >> 10) % NH_;
  int l  = i & (L_ - 1);
  float s = 0.f, cnt = 0.f;
#pragma unroll
  for (int m = 0; m < M_; ++m) {
    float mk = mmask[be*M_ + m];
    cnt += mk;
    int id = midx[be*M_ + m];
    s += mk * att[(((size_t)b*NH_ + nh)*L_ + id)*L_ + l];
  }
  e_att[i] = s / fmaxf(cnt, 1.f);
}

__global__ __launch_bounds__(256) void k_htatt(
    const float* __restrict__ e_att, const int* __restrict__ hts,
    __bf16* __restrict__ htatt)
{
  int bp = blockIdx.x;
  int b = bp / P_;
  int tid = threadIdx.x;
  int hi = hts[bp*2 + 0], ti = hts[bp*2 + 1];
  const float* ha = e_att + (size_t)(b*NE_ + hi) * NH_ * L_;
  const float* ta = e_att + (size_t)(b*NE_ + ti) * NH_ * L_;
  float vals[4]; float loc = 0.f;
#pragma unroll
  for (int q = 0; q < 4; ++q) {
    int l = tid + q*256;
    float s = 0.f;
#pragma unroll
    for (int nh = 0; nh < NH_; ++nh) s += ha[nh*L_ + l] * ta[nh*L_ + l];
    s *= (1.f / NH_);
    vals[q] = s; loc += s;
  }
  __shared__ float red[4];
  for (int off = 32; off > 0; off >>= 1) loc += __shfl_down(loc, off, 64);
  if ((tid & 63) == 0) red[tid >> 6] = loc;
  __syncthreads();
  float inv = 1.f / (red[0] + red[1] + red[2] + red[3] + 1e-30f);
  __bf16* o = htatt + (size_t)bp * L_;
#pragma unroll
  for (int q = 0; q < 4; ++q) o[tid + q*256] = (__bf16)(vals[q] * inv);
}

__global__ __launch_bounds__(256) void k_entity_pre(
    const float* __restrict__ e_emb, const float* __restrict__ headW,
    const float* __restrict__ tailW, float* __restrict__ hpre,
    float* __restrict__ tpre)
{
  int be = blockIdx.x;
  int sel = blockIdx.y;
  const float* W = sel ? tailW : headW;
  float* out = (sel ? tpre : hpre) + (size_t)be * EMB_;
  __shared__ float emb[H_];
  int tid = threadIdx.x;
  for (int h = tid; h < H_; h += 256) emb[h] = e_emb[(size_t)be*H_ + h];
  __syncthreads();
  for (int o = tid; o < EMB_; o += 256) {
    const float* wr = W + (size_t)o * (2*H_);
    float acc = 0.f;
    for (int d = 0; d < H_; d += 4) {
      float4 u = *reinterpret_cast<const float4*>(wr + d);
      acc += emb[d+0]*u.x + emb[d+1]*u.y + emb[d+2]*u.z + emb[d+3]*u.w;
    }
    out[o] = acc;
  }
}

// tiled fp32 -> bf16 transpose: out[b][c][r] = in[b][r][c]
__global__ __launch_bounds__(256) void k_transpose_bf(
    const float* __restrict__ in, __bf16* __restrict__ out,
    int R, int C, long inStride, long outStride)
{
  __shared__ float t[32][33];
  long ib = (long)blockIdx.z * inStride, ob = (long)blockIdx.z * outStride;
  int c0 = blockIdx.x*32, r0 = blockIdx.y*32;
  int tx = threadIdx.x & 31, ty = threadIdx.x >> 5;
#pragma unroll
  for (int p = 0; p < 4; ++p)
    t[ty + p*8][tx] = in[ib + (long)(r0 + ty + p*8)*C + c0 + tx];
  __syncthreads();
#pragma unroll
  for (int p = 0; p < 4; ++p)
    out[ob + (long)(c0 + ty + p*8)*R + r0 + tx] = (__bf16)t[tx][ty + p*8];
}

// W2t[sel][o][k] = bf16(W[o][H + k])
__global__ __launch_bounds__(256) void k_cvt_w2(
    const float* __restrict__ headW, const float* __restrict__ tailW,
    __bf16* __restrict__ W2t)
{
  int gid = blockIdx.x*256 + threadIdx.x;      // 2*768*768/4 = 294912 total
  int sel = gid / 147456;
  int rem = gid % 147456;
  int o = rem / 192;
  int k4 = (rem % 192) * 4;
  const float* W = sel ? tailW : headW;
  float4 v = *reinterpret_cast<const float4*>(W + (long)o*(2*H_) + H_ + k4);
  __bf16* dst = W2t + (long)sel*H_*H_ + (long)o*H_ + k4;
  dst[0] = (__bf16)v.x; dst[1] = (__bf16)v.y; dst[2] = (__bf16)v.z; dst[3] = (__bf16)v.w;
}

// clsA[row][k] = row<97 ? bf16(clsW[row][k]) : 0   (rows padded to 128)
__global__ __launch_bounds__(256) void k_cvt_cls(
    const float* __restrict__ clsW, __bf16* __restrict__ clsA)
{
  int gid = blockIdx.x*256 + threadIdx.x;      // 128*768/4 = 24576
  int row = gid / 192;
  int k4 = (gid % 192) * 4;
  __bf16* dst = clsA + (long)row*H_ + k4;
  if (row < NC_) {
    float4 v = *reinterpret_cast<const float4*>(clsW + (long)row*H_ + k4);
    dst[0] = (__bf16)v.x; dst[1] = (__bf16)v.y; dst[2] = (__bf16)v.z; dst[3] = (__bf16)v.w;
  } else {
    dst[0] = (__bf16)0.f; dst[1] = (__bf16)0.f; dst[2] = (__bf16)0.f; dst[3] = (__bf16)0.f;
  }
}

// =================== shared NT MFMA GEMM core ===================
// C[64x64] += A[row-major MxK] * Bt[row-major NxK]^T, bf16 in, fp32 acc.
// 256 threads = 4 waves; wave w: rows (w&1)*32, cols (w>>1)*32 of the tile.
__device__ __forceinline__ void gemm_core(
    const __bf16* __restrict__ A, int lda, long aRow0,
    const __bf16* __restrict__ Bt, int ldb, long bRow0,
    int K, __bf16* sm, floatx4 acc[2][2])
{
  const int tid = threadIdx.x;
  const int lid = tid & 63, w = tid >> 6;
  const int ar = (w & 1) * 32, bc = (w >> 1) * 32;
  const int frow = lid & 15, kg = lid >> 4;
  __bf16* As = sm;             // [64][40]
  __bf16* Bs = sm + 64*40;     // [64][40]
  const int srow = tid >> 2, skq = (tid & 3) * 8;
  const __bf16* ag = A + (aRow0 + srow) * (long)lda + skq;
  const __bf16* bg = Bt + (bRow0 + srow) * (long)ldb + skq;
  for (int k0 = 0; k0 < K; k0 += 32) {
    uint4 av = *reinterpret_cast<const uint4*>(ag + k0);
    uint4 bv = *reinterpret_cast<const uint4*>(bg + k0);
    __syncthreads();
    *reinterpret_cast<uint4*>(As + srow*40 + skq) = av;
    *reinterpret_cast<uint4*>(Bs + srow*40 + skq) = bv;
    __syncthreads();
    V16 a0, a1, b0, b1;
    a0.q = *reinterpret_cast<const uint4*>(As + (ar + frow)*40 + kg*8);
    a1.q = *reinterpret_cast<const uint4*>(As + (ar + 16 + frow)*40 + kg*8);
    b0.q = *reinterpret_cast<const uint4*>(Bs + (bc + frow)*40 + kg*8);
    b1.q = *reinterpret_cast<const uint4*>(Bs + (bc + 16 + frow)*40 + kg*8);
    acc[0][0] = __builtin_amdgcn_mfma_f32_16x16x32_bf16(a0.v, b0.v, acc[0][0], 0, 0, 0);
    acc[0][1] = __builtin_amdgcn_mfma_f32_16x16x32_bf16(a0.v, b1.v, acc[0][1], 0, 0, 0);
    acc[1][0] = __builtin_amdgcn_mfma_f32_16x16x32_bf16(a1.v, b0.v, acc[1][0], 0, 0, 0);
    acc[1][1] = __builtin_amdgcn_mfma_f32_16x16x32_bf16(a1.v, b1.v, acc[1][1], 0, 0, 0);
  }
}

// rs[b*600+p][h] = sum_l htatt[b*600+p][l] * seqT[b][h][l]
__global__ __launch_bounds__(256) void k_rs_mfma(
    const __bf16* __restrict__ htatt, const __bf16* __restrict__ seqT,
    __bf16* __restrict__ rs)
{
  __shared__ __bf16 sm[2*64*40];
  int b = blockIdx.z, p0 = blockIdx.y*64, h0 = blockIdx.x*64;
  floatx4 acc[2][2] = {};
  gemm_core(htatt, L_, (long)b*P_ + p0, seqT + (long)b*H_*L_, L_, h0, L_, sm, acc);
  int lid = threadIdx.x & 63, w = threadIdx.x >> 6;
  int ar = (w&1)*32, bc = (w>>1)*32, frow = lid&15, kg = lid>>4;
#pragma unroll
  for (int i = 0; i < 2; ++i)
#pragma unroll
    for (int r = 0; r < 4; ++r) {
      int p = p0 + ar + i*16 + kg*4 + r;
      if (p < P_) {
#pragma unroll
        for (int j = 0; j < 2; ++j)
          rs[((long)b*P_ + p)*H_ + h0 + bc + j*16 + frow] = (__bf16)acc[i][j][r];
      }
    }
}

// hs/ts = tanh(pre[gather] + rs @ W2t^T + bias), stored bf16
__global__ __launch_bounds__(256) void k_extract_mfma(
    const __bf16* __restrict__ rs, const __bf16* __restrict__ W2t,
    const float* __restrict__ headb, const float* __restrict__ tailb,
    const float* __restrict__ hpre, const float* __restrict__ tpre,
    const int* __restrict__ hts, __bf16* __restrict__ hs, __bf16* __restrict__ ts)
{
  __shared__ __bf16 sm[2*64*40];
  int sel = blockIdx.z, r0 = blockIdx.y*64, o0 = blockIdx.x*64;
  const float* bias = sel ? tailb : headb;
  const float* pre = sel ? tpre : hpre;
  __bf16* out = sel ? ts : hs;
  floatx4 acc[2][2] = {};
  gemm_core(rs, H_, r0, W2t + (long)sel*H_*H_, H_, o0, H_, sm, acc);
  int lid = threadIdx.x & 63, w = threadIdx.x >> 6;
  int ar = (w&1)*32, bc = (w>>1)*32, frow = lid&15, kg = lid>>4;
#pragma unroll
  for (int i = 0; i < 2; ++i)
#pragma unroll
    for (int r = 0; r < 4; ++r) {
      int row = r0 + ar + i*16 + kg*4 + r;
      if (row < B_*P_) {
        int b = row / P_;
        int e = hts[row*2 + sel];
        const float* prow = pre + (long)(b*NE_ + e) * EMB_;
#pragma unroll
        for (int j = 0; j < 2; ++j) {
          int o = o0 + bc + j*16 + frow;
          out[(long)row*EMB_ + o] = (__bf16)tanhf(acc[i][j][r] + prow[o] + bias[o]);
        }
      }
    }
}

// WcT[c][n] = sum_h clsA[c][h] * projWT[n][h]   (c padded to 128 rows)
__global__ __launch_bounds__(256) void k_wc_mfma(
    const __bf16* __restrict__ clsA, const __bf16* __restrict__ projWT,
    __bf16* __restrict__ WcT)
{
  __shared__ __bf16 sm[2*64*40];
  int n0 = blockIdx.x*64, r0 = blockIdx.y*64;
  floatx4 acc[2][2] = {};
  gemm_core(clsA, H_, r0, projWT, H_, n0, H_, sm, acc);
  int lid = threadIdx.x & 63, w = threadIdx.x >> 6;
  int ar = (w&1)*32, bc = (w>>1)*32, frow = lid&15, kg = lid>>4;
#pragma unroll
  for (int i = 0; i < 2; ++i)
#pragma unroll
    for (int r = 0; r < 4; ++r) {
      int c = r0 + ar + i*16 + kg*4 + r;
#pragma unroll
      for (int j = 0; j < 2; ++j)
        WcT[(long)c*(EMB_*BS_) + n0 + bc + j*16 + frow] = (__bf16)acc[i][j][r];
    }
}

// logits partials: bl(hs,ts) @ WcT^T, A-fragments generated in registers
__global__ __launch_bounds__(512) void k_logits_mfma(
    const __bf16* __restrict__ hs, const __bf16* __restrict__ ts,
    const __bf16* __restrict__ WcT, float* __restrict__ partial)
{
  int r0 = blockIdx.x * 16;
  int kh = blockIdx.y;
  int tid = threadIdx.x;
  int w = tid >> 6, lid = tid & 63;
  int frow = lid & 15, kg = lid >> 4;
  int row = r0 + frow;
  long hsrow = (long)row * EMB_;
  floatx4 acc[7] = {};
  int kbase0 = kh*6144 + w*768;
  for (int s = 0; s < 24; ++s) {
    int kb = kbase0 + s*32 + kg*8;
    int q16 = (kb >> 8) << 4;
    int ii = (kb >> 4) & 15;
    int jj0 = kb & 15;
    float hv = (float)hs[hsrow + q16 + ii];
    V16 tsv; tsv.q = *reinterpret_cast<const uint4*>(ts + hsrow + q16 + jj0);
    bf16x8 af;
#pragma unroll
    for (int j = 0; j < 8; ++j) af[j] = (__bf16)(hv * (float)tsv.b[j]);
#pragma unroll
    for (int f = 0; f < 7; ++f) {
      V16 bv; bv.q = *reinterpret_cast<const uint4*>(WcT + (long)(f*16 + frow)*(EMB_*BS_) + kb);
      acc[f] = __builtin_amdgcn_mfma_f32_16x16x32_bf16(af, bv.v, acc[f], 0, 0, 0);
    }
  }
  __shared__ float red[8][16][112];
#pragma unroll
  for (int f = 0; f < 7; ++f)
#pragma unroll
    for (int r = 0; r < 4; ++r)
      red[w][kg*4 + r][f*16 + frow] = acc[f][r];
  __syncthreads();
  for (int e = tid; e < 16*112; e += 512) {
    int rr = e / 112, cc = e % 112;
    float s = 0.f;
#pragma unroll
    for (int ww = 0; ww < 8; ++ww) s += red[ww][rr][cc];
    partial[((long)kh*B_*P_ + r0 + rr)*112 + cc] = s;
  }
}

__global__ __launch_bounds__(256) void k_lred(
    const float* __restrict__ partial, const float* __restrict__ clsb,
    float* __restrict__ out)
{
  int gid = blockIdx.x*256 + threadIdx.x;   // 2400*112
  if (gid >= B_*P_*112) return;
  int row = gid / 112, c = gid % 112;
  if (c < NC_)
    out[(long)row*NC_ + c] = partial[(long)row*112 + c]
                           + partial[((long)B_*P_ + row)*112 + c] + clsb[c];
}

extern "C" void kernel_launch(void* const* d_in, const int* in_sizes, int n_in,
                              void* d_out, int out_size, void* d_ws, size_t ws_size,
                              hipStream_t stream) {
  const float* seq   = (const float*)d_in[0];
  const float* att   = (const float*)d_in[1];
  const float* headW = (const float*)d_in[2];
  const float* headb = (const float*)d_in[3];
  const float* tailW = (const float*)d_in[4];
  const float* tailb = (const float*)d_in[5];
  const float* projW = (const float*)d_in[6];
  const float* clsW  = (const float*)d_in[7];
  const float* clsb  = (const float*)d_in[8];
  const float* mmask = (const float*)d_in[9];
  const int* midx = (const int*)d_in[10];
  const int* hts  = (const int*)d_in[11];

  char* p = (char*)d_ws;
  auto alloc_f = [&](size_t n){ float* r = (float*)p; p += n*sizeof(float); return r; };
  auto alloc_b = [&](size_t n){ __bf16* r = (__bf16*)p; p += n*2; return r; };
  float* e_emb   = alloc_f((size_t)B_*NE_*H_);
  float* e_att   = alloc_f((size_t)B_*NE_*NH_*L_);
  float* hpre    = alloc_f((size_t)B_*NE_*EMB_);
  float* tpre    = alloc_f((size_t)B_*NE_*EMB_);
  float* partial = alloc_f((size_t)2*B_*P_*112);
  __bf16* htattb = alloc_b((size_t)2464*L_);
  __bf16* seqT   = alloc_b((size_t)B_*H_*L_);
  __bf16* rsb    = alloc_b((size_t)2432*H_);
  __bf16* W2t    = alloc_b((size_t)2*H_*H_);
  __bf16* clsA   = alloc_b((size_t)128*H_);
  __bf16* WcT    = alloc_b((size_t)128*EMB_*BS_);
  __bf16* projWT = alloc_b((size_t)EMB_*BS_*H_);
  // hs/ts alias projWT's region (dead after k_wc_mfma; 2*1.84M <= 9.44M elems)
  __bf16* hsb = projWT;
  __bf16* tsb = projWT + (size_t)B_*P_*EMB_;

  k_entity_pool<<<B_*NE_, 256, 0, stream>>>(seq, mmask, midx, e_emb);
  k_entity_att<<<(B_*NE_*NH_*L_)/256, 256, 0, stream>>>(att, mmask, midx, e_att);
  k_cvt_cls<<<(128*H_/4)/256, 256, 0, stream>>>(clsW, clsA);
  k_transpose_bf<<<dim3(EMB_*BS_/32, H_/32, 1), 256, 0, stream>>>(
      projW, projWT, H_, EMB_*BS_, 0, 0);
  k_wc_mfma<<<dim3(EMB_*BS_/64, 2), 256, 0, stream>>>(clsA, projWT, WcT);
  k_transpose_bf<<<dim3(H_/32, L_/32, B_), 256, 0, stream>>>(
      seq, seqT, L_, H_, (long)L_*H_, (long)H_*L_);
  k_htatt<<<B_*P_, 256, 0, stream>>>(e_att, hts, htattb);
  k_rs_mfma<<<dim3(H_/64, 10, B_), 256, 0, stream>>>(htattb, seqT, rsb);
  k_entity_pre<<<dim3(B_*NE_, 2), 256, 0, stream>>>(e_emb, headW, tailW, hpre, tpre);
  k_cvt_w2<<<(2*H_*H_/4)/256, 256, 0, stream>>>(headW, tailW, W2t);
  k_extract_mfma<<<dim3(EMB_/64, 38, 2), 256, 0, stream>>>(
      rsb, W2t, headb, tailb, hpre, tpre, hts, hsb, tsb);
  k_logits_mfma<<<dim3(150, 2), 512, 0, stream>>>(hsb, tsb, WcT, partial);
  k_lred<<<(B_*P_*112 + 255)/256, 256, 0, stream>>>(partial, clsb, (float*)d_out);
}

// Round 4
// 455.227 us; speedup vs baseline: 2.3207x; 1.1820x over previous
//
#include <hip/hip_runtime.h>
#include <cmath>

#define B_   4
#define L_   1024
#define H_   768
#define NH_  12
#define NE_  30
#define M_   6
#define P_   600
#define EMB_ 768
#define BS_  16
#define NC_  97

typedef __bf16 bf16x8 __attribute__((ext_vector_type(8)));
typedef float floatx4 __attribute__((ext_vector_type(4)));

union V16 { uint4 q; __bf16 b[8]; bf16x8 v; };
union V8  { unsigned long long u; __bf16 b[4]; };

// =================== small pre/post kernels ===================

// e_embB[be][h] (bf16, rows 120..127 left as-is/garbage)
__global__ __launch_bounds__(256) void k_entity_pool(
    const float* __restrict__ seq, const float* __restrict__ mmask,
    const int* __restrict__ midx, __bf16* __restrict__ e_embB)
{
  int be = blockIdx.x;
  int tid = threadIdx.x;
  int idx[M_]; float msk[M_];
#pragma unroll
  for (int m = 0; m < M_; ++m) {
    idx[m] = midx[be * M_ + m];
    msk[m] = mmask[be * M_ + m];
  }
  int b = be / NE_;
  const float* sb = seq + (size_t)b * L_ * H_;
  for (int h = tid; h < H_; h += 256) {
    float v[M_]; float mx = -3.0e38f;
#pragma unroll
    for (int m = 0; m < M_; ++m) {
      float x = (msk[m] > 0.f) ? sb[(size_t)idx[m] * H_ + h] : -1e30f;
      v[m] = x; mx = fmaxf(mx, x);
    }
    float s = 0.f;
#pragma unroll
    for (int m = 0; m < M_; ++m) s += expf(v[m] - mx);
    e_embB[(size_t)be * H_ + h] = (__bf16)(mx + logf(s));
  }
}

// e_att bf16, float4 gathers; one thread = 4 consecutive l
__global__ __launch_bounds__(256) void k_entity_att(
    const float* __restrict__ att, const float* __restrict__ mmask,
    const int* __restrict__ midx, __bf16* __restrict__ e_att)
{
  int i = blockIdx.x * 256 + threadIdx.x;      // quads: B*NE*NH*256
  int l4 = (i & 255) * 4;
  int nh = (i >> 8) % NH_;
  int be = i / (256 * NH_);
  int b  = be / NE_;
  float s0=0.f, s1=0.f, s2=0.f, s3=0.f, cnt=0.f;
#pragma unroll
  for (int m = 0; m < M_; ++m) {
    float mk = mmask[be*M_ + m];
    cnt += mk;
    int id = midx[be*M_ + m];
    float4 a = *reinterpret_cast<const float4*>(
        att + (((size_t)b*NH_ + nh)*L_ + id)*L_ + l4);
    s0 += mk*a.x; s1 += mk*a.y; s2 += mk*a.z; s3 += mk*a.w;
  }
  float inv = 1.f / fmaxf(cnt, 1.f);
  V8 o;
  o.b[0]=(__bf16)(s0*inv); o.b[1]=(__bf16)(s1*inv);
  o.b[2]=(__bf16)(s2*inv); o.b[3]=(__bf16)(s3*inv);
  *reinterpret_cast<unsigned long long*>(e_att + ((size_t)be*NH_ + nh)*L_ + l4) = o.u;
}

// ht_att normalized, bf16 in/out; thread = 4 consecutive l
__global__ __launch_bounds__(256) void k_htatt(
    const __bf16* __restrict__ e_att, const int* __restrict__ hts,
    __bf16* __restrict__ htatt)
{
  int bp = blockIdx.x;
  int b = bp / P_;
  int tid = threadIdx.x;
  int hi = hts[bp*2 + 0], ti = hts[bp*2 + 1];
  const __bf16* ha = e_att + (size_t)(b*NE_ + hi) * NH_ * L_;
  const __bf16* ta = e_att + (size_t)(b*NE_ + ti) * NH_ * L_;
  int l4 = tid * 4;
  float v[4] = {0.f,0.f,0.f,0.f};
#pragma unroll
  for (int nh = 0; nh < NH_; ++nh) {
    V8 x, y;
    x.u = *reinterpret_cast<const unsigned long long*>(ha + nh*L_ + l4);
    y.u = *reinterpret_cast<const unsigned long long*>(ta + nh*L_ + l4);
#pragma unroll
    for (int q = 0; q < 4; ++q) v[q] += (float)x.b[q] * (float)y.b[q];
  }
  float loc = 0.f;
#pragma unroll
  for (int q = 0; q < 4; ++q) { v[q] *= (1.f/NH_); loc += v[q]; }
  __shared__ float red[4];
  for (int off = 32; off > 0; off >>= 1) loc += __shfl_down(loc, off, 64);
  if ((tid & 63) == 0) red[tid >> 6] = loc;
  __syncthreads();
  float inv = 1.f / (red[0] + red[1] + red[2] + red[3] + 1e-30f);
  V8 o;
#pragma unroll
  for (int q = 0; q < 4; ++q) o.b[q] = (__bf16)(v[q] * inv);
  *reinterpret_cast<unsigned long long*>(htatt + (size_t)bp*L_ + l4) = o.u;
}

// fused weight converts: Wt[2][768][1536] (full-width bf16 head/tail W) + clsA[128][768]
__global__ __launch_bounds__(256) void k_cvt_weights(
    const float* __restrict__ headW, const float* __restrict__ tailW,
    const float* __restrict__ clsW, __bf16* __restrict__ Wt,
    __bf16* __restrict__ clsA)
{
  int gid = blockIdx.x*256 + threadIdx.x;   // 614400 quads total
  if (gid < 2*H_*384) {                     // W part: 589824 quads
    int sel = gid / (H_*384);
    int rem = gid % (H_*384);
    int o = rem / 384;
    int k4 = (rem % 384) * 4;
    const float* W = sel ? tailW : headW;
    float4 v = *reinterpret_cast<const float4*>(W + (long)o*(2*H_) + k4);
    V8 d; d.b[0]=(__bf16)v.x; d.b[1]=(__bf16)v.y; d.b[2]=(__bf16)v.z; d.b[3]=(__bf16)v.w;
    *reinterpret_cast<unsigned long long*>(Wt + ((long)sel*H_ + o)*(2*H_) + k4) = d.u;
  } else {
    int rem = gid - 2*H_*384;               // 24576 quads
    int row = rem / 192;
    int k4 = (rem % 192) * 4;
    V8 d;
    if (row < NC_) {
      float4 v = *reinterpret_cast<const float4*>(clsW + (long)row*H_ + k4);
      d.b[0]=(__bf16)v.x; d.b[1]=(__bf16)v.y; d.b[2]=(__bf16)v.z; d.b[3]=(__bf16)v.w;
    } else {
      d.b[0]=d.b[1]=d.b[2]=d.b[3]=(__bf16)0.f;
    }
    *reinterpret_cast<unsigned long long*>(clsA + (long)row*H_ + k4) = d.u;
  }
}

// tiled fp32 -> bf16 transpose: out[b][c][r] = in[b][r][c]
__global__ __launch_bounds__(256) void k_transpose_bf(
    const float* __restrict__ in, __bf16* __restrict__ out,
    int R, int C, long inStride, long outStride)
{
  __shared__ float t[32][33];
  long ib = (long)blockIdx.z * inStride, ob = (long)blockIdx.z * outStride;
  int c0 = blockIdx.x*32, r0 = blockIdx.y*32;
  int tx = threadIdx.x & 31, ty = threadIdx.x >> 5;
#pragma unroll
  for (int p = 0; p < 4; ++p)
    t[ty + p*8][tx] = in[ib + (long)(r0 + ty + p*8)*C + c0 + tx];
  __syncthreads();
#pragma unroll
  for (int p = 0; p < 4; ++p)
    out[ob + (long)(c0 + ty + p*8)*R + r0 + tx] = (__bf16)t[tx][ty + p*8];
}

// =================== shared NT MFMA GEMM core ===================
__device__ __forceinline__ void gemm_core(
    const __bf16* __restrict__ A, int lda, long aRow0,
    const __bf16* __restrict__ Bt, int ldb, long bRow0,
    int K, __bf16* sm, floatx4 acc[2][2])
{
  const int tid = threadIdx.x;
  const int lid = tid & 63, w = tid >> 6;
  const int ar = (w & 1) * 32, bc = (w >> 1) * 32;
  const int frow = lid & 15, kg = lid >> 4;
  __bf16* As = sm;             // [64][40]
  __bf16* Bs = sm + 64*40;     // [64][40]
  const int srow = tid >> 2, skq = (tid & 3) * 8;
  const __bf16* ag = A + (aRow0 + srow) * (long)lda + skq;
  const __bf16* bg = Bt + (bRow0 + srow) * (long)ldb + skq;
  for (int k0 = 0; k0 < K; k0 += 32) {
    uint4 av = *reinterpret_cast<const uint4*>(ag + k0);
    uint4 bv = *reinterpret_cast<const uint4*>(bg + k0);
    __syncthreads();
    *reinterpret_cast<uint4*>(As + srow*40 + skq) = av;
    *reinterpret_cast<uint4*>(Bs + srow*40 + skq) = bv;
    __syncthreads();
    V16 a0, a1, b0, b1;
    a0.q = *reinterpret_cast<const uint4*>(As + (ar + frow)*40 + kg*8);
    a1.q = *reinterpret_cast<const uint4*>(As + (ar + 16 + frow)*40 + kg*8);
    b0.q = *reinterpret_cast<const uint4*>(Bs + (bc + frow)*40 + kg*8);
    b1.q = *reinterpret_cast<const uint4*>(Bs + (bc + 16 + frow)*40 + kg*8);
    acc[0][0] = __builtin_amdgcn_mfma_f32_16x16x32_bf16(a0.v, b0.v, acc[0][0], 0, 0, 0);
    acc[0][1] = __builtin_amdgcn_mfma_f32_16x16x32_bf16(a0.v, b1.v, acc[0][1], 0, 0, 0);
    acc[1][0] = __builtin_amdgcn_mfma_f32_16x16x32_bf16(a1.v, b0.v, acc[1][0], 0, 0, 0);
    acc[1][1] = __builtin_amdgcn_mfma_f32_16x16x32_bf16(a1.v, b1.v, acc[1][1], 0, 0, 0);
  }
}

// rs[b*600+p][h]
__global__ __launch_bounds__(256) void k_rs_mfma(
    const __bf16* __restrict__ htatt, const __bf16* __restrict__ seqT,
    __bf16* __restrict__ rs)
{
  __shared__ __bf16 sm[2*64*40];
  int b = blockIdx.z, p0 = blockIdx.y*64, h0 = blockIdx.x*64;
  floatx4 acc[2][2] = {};
  gemm_core(htatt, L_, (long)b*P_ + p0, seqT + (long)b*H_*L_, L_, h0, L_, sm, acc);
  int lid = threadIdx.x & 63, w = threadIdx.x >> 6;
  int ar = (w&1)*32, bc = (w>>1)*32, frow = lid&15, kg = lid>>4;
#pragma unroll
  for (int i = 0; i < 2; ++i)
#pragma unroll
    for (int r = 0; r < 4; ++r) {
      int p = p0 + ar + i*16 + kg*4 + r;
      if (p < P_) {
#pragma unroll
        for (int j = 0; j < 2; ++j)
          rs[((long)b*P_ + p)*H_ + h0 + bc + j*16 + frow] = (__bf16)acc[i][j][r];
      }
    }
}

// hpre/tpre[be][o] = e_emb[be] . W[o][:H]  via MFMA
__global__ __launch_bounds__(256) void k_pre_mfma(
    const __bf16* __restrict__ e_embB, const __bf16* __restrict__ Wt,
    float* __restrict__ hpre, float* __restrict__ tpre)
{
  __shared__ __bf16 sm[2*64*40];
  int sel = blockIdx.z, r0 = blockIdx.y*64, o0 = blockIdx.x*64;
  floatx4 acc[2][2] = {};
  gemm_core(e_embB, H_, r0, Wt + (long)sel*H_*(2*H_), 2*H_, o0, H_, sm, acc);
  float* out = sel ? tpre : hpre;
  int lid = threadIdx.x & 63, w = threadIdx.x >> 6;
  int ar = (w&1)*32, bc = (w>>1)*32, frow = lid&15, kg = lid>>4;
#pragma unroll
  for (int i = 0; i < 2; ++i)
#pragma unroll
    for (int r = 0; r < 4; ++r) {
      int be = r0 + ar + i*16 + kg*4 + r;
      if (be < B_*NE_) {
#pragma unroll
        for (int j = 0; j < 2; ++j)
          out[(long)be*EMB_ + o0 + bc + j*16 + frow] = acc[i][j][r];
      }
    }
}

// hs/ts = tanh(pre[gather] + rs @ W[:,H:]^T + bias)
__global__ __launch_bounds__(256) void k_extract_mfma(
    const __bf16* __restrict__ rs, const __bf16* __restrict__ Wt,
    const float* __restrict__ headb, const float* __restrict__ tailb,
    const float* __restrict__ hpre, const float* __restrict__ tpre,
    const int* __restrict__ hts, __bf16* __restrict__ hs, __bf16* __restrict__ ts)
{
  __shared__ __bf16 sm[2*64*40];
  int sel = blockIdx.z, r0 = blockIdx.y*64, o0 = blockIdx.x*64;
  const float* bias = sel ? tailb : headb;
  const float* pre = sel ? tpre : hpre;
  __bf16* out = sel ? ts : hs;
  floatx4 acc[2][2] = {};
  gemm_core(rs, H_, r0, Wt + (long)sel*H_*(2*H_) + H_, 2*H_, o0, H_, sm, acc);
  int lid = threadIdx.x & 63, w = threadIdx.x >> 6;
  int ar = (w&1)*32, bc = (w>>1)*32, frow = lid&15, kg = lid>>4;
#pragma unroll
  for (int i = 0; i < 2; ++i)
#pragma unroll
    for (int r = 0; r < 4; ++r) {
      int row = r0 + ar + i*16 + kg*4 + r;
      if (row < B_*P_) {
        int b = row / P_;
        int e = hts[row*2 + sel];
        const float* prow = pre + (long)(b*NE_ + e) * EMB_;
#pragma unroll
        for (int j = 0; j < 2; ++j) {
          int o = o0 + bc + j*16 + frow;
          out[(long)row*EMB_ + o] = (__bf16)tanhf(acc[i][j][r] + prow[o] + bias[o]);
        }
      }
    }
}

// WcT[c][n] = sum_h clsA[c][h] * projWT[n][h]
__global__ __launch_bounds__(256) void k_wc_mfma(
    const __bf16* __restrict__ clsA, const __bf16* __restrict__ projWT,
    __bf16* __restrict__ WcT)
{
  __shared__ __bf16 sm[2*64*40];
  int n0 = blockIdx.x*64, r0 = blockIdx.y*64;
  floatx4 acc[2][2] = {};
  gemm_core(clsA, H_, r0, projWT, H_, n0, H_, sm, acc);
  int lid = threadIdx.x & 63, w = threadIdx.x >> 6;
  int ar = (w&1)*32, bc = (w>>1)*32, frow = lid&15, kg = lid>>4;
#pragma unroll
  for (int i = 0; i < 2; ++i)
#pragma unroll
    for (int r = 0; r < 4; ++r) {
      int c = r0 + ar + i*16 + kg*4 + r;
#pragma unroll
      for (int j = 0; j < 2; ++j)
        WcT[(long)c*(EMB_*BS_) + n0 + bc + j*16 + frow] = (__bf16)acc[i][j][r];
    }
}

// logits partials over 4 K-slices
__global__ __launch_bounds__(512) void k_logits_mfma(
    const __bf16* __restrict__ hs, const __bf16* __restrict__ ts,
    const __bf16* __restrict__ WcT, float* __restrict__ partial)
{
  int r0 = blockIdx.x * 16;
  int kh = blockIdx.y;                 // 0..3
  int tid = threadIdx.x;
  int w = tid >> 6, lid = tid & 63;
  int frow = lid & 15, kg = lid >> 4;
  int row = r0 + frow;
  long hsrow = (long)row * EMB_;
  floatx4 acc[7] = {};
  int kbase0 = kh*3072 + w*384;
  for (int s = 0; s < 12; ++s) {
    int kb = kbase0 + s*32 + kg*8;
    int q16 = (kb >> 8) << 4;
    int ii = (kb >> 4) & 15;
    int jj0 = kb & 15;
    float hv = (float)hs[hsrow + q16 + ii];
    V16 tsv; tsv.q = *reinterpret_cast<const uint4*>(ts + hsrow + q16 + jj0);
    bf16x8 af;
#pragma unroll
    for (int j = 0; j < 8; ++j) af[j] = (__bf16)(hv * (float)tsv.b[j]);
#pragma unroll
    for (int f = 0; f < 7; ++f) {
      V16 bv; bv.q = *reinterpret_cast<const uint4*>(WcT + (long)(f*16 + frow)*(EMB_*BS_) + kb);
      acc[f] = __builtin_amdgcn_mfma_f32_16x16x32_bf16(af, bv.v, acc[f], 0, 0, 0);
    }
  }
  __shared__ float red[8][16][112];
#pragma unroll
  for (int f = 0; f < 7; ++f)
#pragma unroll
    for (int r = 0; r < 4; ++r)
      red[w][kg*4 + r][f*16 + frow] = acc[f][r];
  __syncthreads();
  for (int e = tid; e < 16*112; e += 512) {
    int rr = e / 112, cc = e % 112;
    float s = 0.f;
#pragma unroll
    for (int ww = 0; ww < 8; ++ww) s += red[ww][rr][cc];
    partial[((long)kh*B_*P_ + r0 + rr)*112 + cc] = s;
  }
}

__global__ __launch_bounds__(256) void k_lred(
    const float* __restrict__ partial, const float* __restrict__ clsb,
    float* __restrict__ out)
{
  int gid = blockIdx.x*256 + threadIdx.x;
  if (gid >= B_*P_*112) return;
  int row = gid / 112, c = gid % 112;
  if (c < NC_) {
    float s = clsb[c];
#pragma unroll
    for (int q = 0; q < 4; ++q)
      s += partial[((long)q*B_*P_ + row)*112 + c];
    out[(long)row*NC_ + c] = s;
  }
}

extern "C" void kernel_launch(void* const* d_in, const int* in_sizes, int n_in,
                              void* d_out, int out_size, void* d_ws, size_t ws_size,
                              hipStream_t stream) {
  const float* seq   = (const float*)d_in[0];
  const float* att   = (const float*)d_in[1];
  const float* headW = (const float*)d_in[2];
  const float* headb = (const float*)d_in[3];
  const float* tailW = (const float*)d_in[4];
  const float* tailb = (const float*)d_in[5];
  const float* projW = (const float*)d_in[6];
  const float* clsW  = (const float*)d_in[7];
  const float* clsb  = (const float*)d_in[8];
  const float* mmask = (const float*)d_in[9];
  const int* midx = (const int*)d_in[10];
  const int* hts  = (const int*)d_in[11];

  char* p = (char*)d_ws;
  auto alloc_f = [&](size_t n){ float* r = (float*)p; p += n*sizeof(float); return r; };
  auto alloc_b = [&](size_t n){ __bf16* r = (__bf16*)p; p += n*2; return r; };
  float* hpre    = alloc_f((size_t)B_*NE_*EMB_);
  float* tpre    = alloc_f((size_t)B_*NE_*EMB_);
  float* partial = alloc_f((size_t)4*B_*P_*112);
  __bf16* e_embB = alloc_b((size_t)128*H_);
  __bf16* e_att  = alloc_b((size_t)B_*NE_*NH_*L_);
  __bf16* htattb = alloc_b((size_t)2464*L_);
  __bf16* seqT   = alloc_b((size_t)B_*H_*L_);
  __bf16* rsb    = alloc_b((size_t)2432*H_);
  __bf16* Wt     = alloc_b((size_t)2*H_*2*H_);
  __bf16* clsA   = alloc_b((size_t)128*H_);
  __bf16* WcT    = alloc_b((size_t)128*EMB_*BS_);
  __bf16* projWT = alloc_b((size_t)EMB_*BS_*H_);
  // hs/ts alias projWT (dead after k_wc_mfma)
  __bf16* hsb = projWT;
  __bf16* tsb = projWT + (size_t)B_*P_*EMB_;

  k_cvt_weights<<<2400, 256, 0, stream>>>(headW, tailW, clsW, Wt, clsA);
  k_transpose_bf<<<dim3(EMB_*BS_/32, H_/32, 1), 256, 0, stream>>>(
      projW, projWT, H_, EMB_*BS_, 0, 0);
  k_wc_mfma<<<dim3(EMB_*BS_/64, 2), 256, 0, stream>>>(clsA, projWT, WcT);
  k_entity_pool<<<B_*NE_, 256, 0, stream>>>(seq, mmask, midx, e_embB);
  k_entity_att<<<(B_*NE_*NH_*256)/256, 256, 0, stream>>>(att, mmask, midx, e_att);
  k_transpose_bf<<<dim3(H_/32, L_/32, B_), 256, 0, stream>>>(
      seq, seqT, L_, H_, (long)L_*H_, (long)H_*L_);
  k_htatt<<<B_*P_, 256, 0, stream>>>(e_att, hts, htattb);
  k_rs_mfma<<<dim3(H_/64, 10, B_), 256, 0, stream>>>(htattb, seqT, rsb);
  k_pre_mfma<<<dim3(EMB_/64, 2, 2), 256, 0, stream>>>(e_embB, Wt, hpre, tpre);
  k_extract_mfma<<<dim3(EMB_/64, 38, 2), 256, 0, stream>>>(
      rsb, Wt, headb, tailb, hpre, tpre, hts, hsb, tsb);
  k_logits_mfma<<<dim3(150, 4), 512, 0, stream>>>(hsb, tsb, WcT, partial);
  k_lred<<<(B_*P_*112 + 255)/256, 256, 0, stream>>>(partial, clsb, (float*)d_out);
}

// Round 5
// 451.657 us; speedup vs baseline: 2.3391x; 1.0079x over previous
//
#include <hip/hip_runtime.h>
#include <cmath>

#define B_   4
#define L_   1024
#define H_   768
#define NH_  12
#define NE_  30
#define M_   6
#define P_   600
#define EMB_ 768
#define BS_  16
#define NC_  97

typedef __bf16 bf16x8 __attribute__((ext_vector_type(8)));
typedef float floatx4 __attribute__((ext_vector_type(4)));

union V16 { uint4 q; __bf16 b[8]; bf16x8 v; };
union V8  { unsigned long long u; __bf16 b[4]; };

// =================== shared NT MFMA GEMM core ===================
__device__ __forceinline__ void gemm_core(
    const __bf16* __restrict__ A, int lda, long aRow0,
    const __bf16* __restrict__ Bt, int ldb, long bRow0,
    int K, __bf16* sm, floatx4 acc[2][2])
{
  const int tid = threadIdx.x;
  const int lid = tid & 63, w = tid >> 6;
  const int ar = (w & 1) * 32, bc = (w >> 1) * 32;
  const int frow = lid & 15, kg = lid >> 4;
  __bf16* As = sm;             // [64][40]
  __bf16* Bs = sm + 64*40;     // [64][40]
  const int srow = tid >> 2, skq = (tid & 3) * 8;
  const __bf16* ag = A + (aRow0 + srow) * (long)lda + skq;
  const __bf16* bg = Bt + (bRow0 + srow) * (long)ldb + skq;
  for (int k0 = 0; k0 < K; k0 += 32) {
    uint4 av = *reinterpret_cast<const uint4*>(ag + k0);
    uint4 bv = *reinterpret_cast<const uint4*>(bg + k0);
    __syncthreads();
    *reinterpret_cast<uint4*>(As + srow*40 + skq) = av;
    *reinterpret_cast<uint4*>(Bs + srow*40 + skq) = bv;
    __syncthreads();
    V16 a0, a1, b0, b1;
    a0.q = *reinterpret_cast<const uint4*>(As + (ar + frow)*40 + kg*8);
    a1.q = *reinterpret_cast<const uint4*>(As + (ar + 16 + frow)*40 + kg*8);
    b0.q = *reinterpret_cast<const uint4*>(Bs + (bc + frow)*40 + kg*8);
    b1.q = *reinterpret_cast<const uint4*>(Bs + (bc + 16 + frow)*40 + kg*8);
    acc[0][0] = __builtin_amdgcn_mfma_f32_16x16x32_bf16(a0.v, b0.v, acc[0][0], 0, 0, 0);
    acc[0][1] = __builtin_amdgcn_mfma_f32_16x16x32_bf16(a0.v, b1.v, acc[0][1], 0, 0, 0);
    acc[1][0] = __builtin_amdgcn_mfma_f32_16x16x32_bf16(a1.v, b0.v, acc[1][0], 0, 0, 0);
    acc[1][1] = __builtin_amdgcn_mfma_f32_16x16x32_bf16(a1.v, b1.v, acc[1][1], 0, 0, 0);
  }
}

// =================== STAGE 1: fused prep ===================
// blocks: [0,2400) cvt weights | [2400,11616) transpose projW |
// [11616,14688) transpose seq | [14688,14808) entity_pool | [14808,16248) entity_att
#define S1_CVT  2400
#define S1_TPW  9216
#define S1_TPS  3072
#define S1_POOL 120
#define S1_ATT  1440

__device__ __forceinline__ void transpose_body(
    const float* __restrict__ in, __bf16* __restrict__ out,
    int R, int C, int bx, int by, float (*t)[33])
{
  int c0 = bx*32, r0 = by*32;
  int tx = threadIdx.x & 31, ty = threadIdx.x >> 5;
#pragma unroll
  for (int p = 0; p < 4; ++p)
    t[ty + p*8][tx] = in[(long)(r0 + ty + p*8)*C + c0 + tx];
  __syncthreads();
#pragma unroll
  for (int p = 0; p < 4; ++p)
    out[(long)(c0 + ty + p*8)*R + r0 + tx] = (__bf16)t[tx][ty + p*8];
}

__global__ __launch_bounds__(256) void k_prep(
    const float* __restrict__ seq, const float* __restrict__ att,
    const float* __restrict__ headW, const float* __restrict__ tailW,
    const float* __restrict__ projW, const float* __restrict__ clsW,
    const float* __restrict__ mmask, const int* __restrict__ midx,
    __bf16* __restrict__ Wt, __bf16* __restrict__ clsA,
    __bf16* __restrict__ projWT, __bf16* __restrict__ seqT,
    __bf16* __restrict__ e_embB, __bf16* __restrict__ e_att)
{
  __shared__ float t[32][33];
  int blk = blockIdx.x;
  int tid = threadIdx.x;
  if (blk < S1_CVT) {
    int gid = blk*256 + tid;
    if (gid < 2*H_*384) {
      int sel = gid / (H_*384);
      int rem = gid % (H_*384);
      int o = rem / 384;
      int k4 = (rem % 384) * 4;
      const float* W = sel ? tailW : headW;
      float4 v = *reinterpret_cast<const float4*>(W + (long)o*(2*H_) + k4);
      V8 d; d.b[0]=(__bf16)v.x; d.b[1]=(__bf16)v.y; d.b[2]=(__bf16)v.z; d.b[3]=(__bf16)v.w;
      *reinterpret_cast<unsigned long long*>(Wt + ((long)sel*H_ + o)*(2*H_) + k4) = d.u;
    } else {
      int rem = gid - 2*H_*384;
      int row = rem / 192;
      int k4 = (rem % 192) * 4;
      V8 d;
      if (row < NC_) {
        float4 v = *reinterpret_cast<const float4*>(clsW + (long)row*H_ + k4);
        d.b[0]=(__bf16)v.x; d.b[1]=(__bf16)v.y; d.b[2]=(__bf16)v.z; d.b[3]=(__bf16)v.w;
      } else {
        d.b[0]=d.b[1]=d.b[2]=d.b[3]=(__bf16)0.f;
      }
      *reinterpret_cast<unsigned long long*>(clsA + (long)row*H_ + k4) = d.u;
    }
  } else if (blk < S1_CVT + S1_TPW) {
    int b = blk - S1_CVT;
    transpose_body(projW, projWT, H_, EMB_*BS_, b % 384, b / 384, t);
  } else if (blk < S1_CVT + S1_TPW + S1_TPS) {
    int b = blk - (S1_CVT + S1_TPW);
    int bx = b % 24, by = (b / 24) % 32, bz = b / (24*32);
    transpose_body(seq + (long)bz*L_*H_, seqT + (long)bz*H_*L_, L_, H_, bx, by, t);
  } else if (blk < S1_CVT + S1_TPW + S1_TPS + S1_POOL) {
    int be = blk - (S1_CVT + S1_TPW + S1_TPS);
    int idx[M_]; float msk[M_];
#pragma unroll
    for (int m = 0; m < M_; ++m) {
      idx[m] = midx[be * M_ + m];
      msk[m] = mmask[be * M_ + m];
    }
    int b = be / NE_;
    const float* sb = seq + (size_t)b * L_ * H_;
    for (int h = tid; h < H_; h += 256) {
      float v[M_]; float mx = -3.0e38f;
#pragma unroll
      for (int m = 0; m < M_; ++m) {
        float x = (msk[m] > 0.f) ? sb[(size_t)idx[m] * H_ + h] : -1e30f;
        v[m] = x; mx = fmaxf(mx, x);
      }
      float s = 0.f;
#pragma unroll
      for (int m = 0; m < M_; ++m) s += expf(v[m] - mx);
      e_embB[(size_t)be * H_ + h] = (__bf16)(mx + logf(s));
    }
  } else {
    int i = (blk - (S1_CVT + S1_TPW + S1_TPS + S1_POOL))*256 + tid;
    int l4 = (i & 255) * 4;
    int nh = (i >> 8) % NH_;
    int be = i / (256 * NH_);
    int b  = be / NE_;
    float s0=0.f, s1=0.f, s2=0.f, s3=0.f, cnt=0.f;
#pragma unroll
    for (int m = 0; m < M_; ++m) {
      float mk = mmask[be*M_ + m];
      cnt += mk;
      int id = midx[be*M_ + m];
      float4 a = *reinterpret_cast<const float4*>(
          att + (((size_t)b*NH_ + nh)*L_ + id)*L_ + l4);
      s0 += mk*a.x; s1 += mk*a.y; s2 += mk*a.z; s3 += mk*a.w;
    }
    float inv = 1.f / fmaxf(cnt, 1.f);
    V8 o;
    o.b[0]=(__bf16)(s0*inv); o.b[1]=(__bf16)(s1*inv);
    o.b[2]=(__bf16)(s2*inv); o.b[3]=(__bf16)(s3*inv);
    *reinterpret_cast<unsigned long long*>(e_att + ((size_t)be*NH_ + nh)*L_ + l4) = o.u;
  }
}

// =================== STAGE 2: fused wc + htatt + pre ===================
// blocks: [0,384) wc | [384,2784) htatt | [2784,2832) pre
#define S2_WC  384
#define S2_HT  2400
#define S2_PRE 48

__global__ __launch_bounds__(256) void k_mid(
    const __bf16* __restrict__ clsA, const __bf16* __restrict__ projWT,
    const __bf16* __restrict__ e_att, const int* __restrict__ hts,
    const __bf16* __restrict__ e_embB, const __bf16* __restrict__ Wt,
    __bf16* __restrict__ WcT, __bf16* __restrict__ htatt,
    float* __restrict__ hpre, float* __restrict__ tpre)
{
  __shared__ __bf16 sm[2*64*40];
  int blk = blockIdx.x;
  int tid = threadIdx.x;
  if (blk < S2_WC) {
    int n0 = (blk % 192)*64, r0 = (blk / 192)*64;
    floatx4 acc[2][2] = {};
    gemm_core(clsA, H_, r0, projWT, H_, n0, H_, sm, acc);
    int lid = tid & 63, w = tid >> 6;
    int ar = (w&1)*32, bc = (w>>1)*32, frow = lid&15, kg = lid>>4;
#pragma unroll
    for (int i = 0; i < 2; ++i)
#pragma unroll
      for (int r = 0; r < 4; ++r) {
        int c = r0 + ar + i*16 + kg*4 + r;
#pragma unroll
        for (int j = 0; j < 2; ++j)
          WcT[(long)c*(EMB_*BS_) + n0 + bc + j*16 + frow] = (__bf16)acc[i][j][r];
      }
  } else if (blk < S2_WC + S2_HT) {
    int bp = blk - S2_WC;
    int b = bp / P_;
    int hi = hts[bp*2 + 0], ti = hts[bp*2 + 1];
    const __bf16* ha = e_att + (size_t)(b*NE_ + hi) * NH_ * L_;
    const __bf16* ta = e_att + (size_t)(b*NE_ + ti) * NH_ * L_;
    int l4 = tid * 4;
    float v[4] = {0.f,0.f,0.f,0.f};
#pragma unroll
    for (int nh = 0; nh < NH_; ++nh) {
      V8 x, y;
      x.u = *reinterpret_cast<const unsigned long long*>(ha + nh*L_ + l4);
      y.u = *reinterpret_cast<const unsigned long long*>(ta + nh*L_ + l4);
#pragma unroll
      for (int q = 0; q < 4; ++q) v[q] += (float)x.b[q] * (float)y.b[q];
    }
    float loc = 0.f;
#pragma unroll
    for (int q = 0; q < 4; ++q) { v[q] *= (1.f/NH_); loc += v[q]; }
    float* red = reinterpret_cast<float*>(sm);
    for (int off = 32; off > 0; off >>= 1) loc += __shfl_down(loc, off, 64);
    if ((tid & 63) == 0) red[tid >> 6] = loc;
    __syncthreads();
    float inv = 1.f / (red[0] + red[1] + red[2] + red[3] + 1e-30f);
    V8 o;
#pragma unroll
    for (int q = 0; q < 4; ++q) o.b[q] = (__bf16)(v[q] * inv);
    *reinterpret_cast<unsigned long long*>(htatt + (size_t)bp*L_ + l4) = o.u;
  } else {
    int tb = blk - (S2_WC + S2_HT);
    int o0 = (tb % 12)*64;
    int r0 = ((tb / 12) & 1)*64;
    int sel = tb / 24;
    floatx4 acc[2][2] = {};
    gemm_core(e_embB, H_, r0, Wt + (long)sel*H_*(2*H_), 2*H_, o0, H_, sm, acc);
    float* out = sel ? tpre : hpre;
    int lid = tid & 63, w = tid >> 6;
    int ar = (w&1)*32, bc = (w>>1)*32, frow = lid&15, kg = lid>>4;
#pragma unroll
    for (int i = 0; i < 2; ++i)
#pragma unroll
      for (int r = 0; r < 4; ++r) {
        int be = r0 + ar + i*16 + kg*4 + r;
        if (be < B_*NE_) {
#pragma unroll
          for (int j = 0; j < 2; ++j)
            out[(long)be*EMB_ + o0 + bc + j*16 + frow] = acc[i][j][r];
        }
      }
  }
}

// =================== STAGE 3: rs ===================
__global__ __launch_bounds__(256) void k_rs_mfma(
    const __bf16* __restrict__ htatt, const __bf16* __restrict__ seqT,
    __bf16* __restrict__ rs)
{
  __shared__ __bf16 sm[2*64*40];
  int b = blockIdx.z, p0 = blockIdx.y*64, h0 = blockIdx.x*64;
  floatx4 acc[2][2] = {};
  gemm_core(htatt, L_, (long)b*P_ + p0, seqT + (long)b*H_*L_, L_, h0, L_, sm, acc);
  int lid = threadIdx.x & 63, w = threadIdx.x >> 6;
  int ar = (w&1)*32, bc = (w>>1)*32, frow = lid&15, kg = lid>>4;
#pragma unroll
  for (int i = 0; i < 2; ++i)
#pragma unroll
    for (int r = 0; r < 4; ++r) {
      int p = p0 + ar + i*16 + kg*4 + r;
      if (p < P_) {
#pragma unroll
        for (int j = 0; j < 2; ++j)
          rs[((long)b*P_ + p)*H_ + h0 + bc + j*16 + frow] = (__bf16)acc[i][j][r];
      }
    }
}

// =================== STAGE 4: extract ===================
__global__ __launch_bounds__(256) void k_extract_mfma(
    const __bf16* __restrict__ rs, const __bf16* __restrict__ Wt,
    const float* __restrict__ headb, const float* __restrict__ tailb,
    const float* __restrict__ hpre, const float* __restrict__ tpre,
    const int* __restrict__ hts, __bf16* __restrict__ hs, __bf16* __restrict__ ts)
{
  __shared__ __bf16 sm[2*64*40];
  int sel = blockIdx.z, r0 = blockIdx.y*64, o0 = blockIdx.x*64;
  const float* bias = sel ? tailb : headb;
  const float* pre = sel ? tpre : hpre;
  __bf16* out = sel ? ts : hs;
  floatx4 acc[2][2] = {};
  gemm_core(rs, H_, r0, Wt + (long)sel*H_*(2*H_) + H_, 2*H_, o0, H_, sm, acc);
  int lid = threadIdx.x & 63, w = threadIdx.x >> 6;
  int ar = (w&1)*32, bc = (w>>1)*32, frow = lid&15, kg = lid>>4;
#pragma unroll
  for (int i = 0; i < 2; ++i)
#pragma unroll
    for (int r = 0; r < 4; ++r) {
      int row = r0 + ar + i*16 + kg*4 + r;
      if (row < B_*P_) {
        int b = row / P_;
        int e = hts[row*2 + sel];
        const float* prow = pre + (long)(b*NE_ + e) * EMB_;
#pragma unroll
        for (int j = 0; j < 2; ++j) {
          int o = o0 + bc + j*16 + frow;
          out[(long)row*EMB_ + o] = (__bf16)tanhf(acc[i][j][r] + prow[o] + bias[o]);
        }
      }
    }
}

// =================== STAGE 5: logits (full-K, direct output) ===================
__global__ __launch_bounds__(512) void k_logits_mfma(
    const __bf16* __restrict__ hs, const __bf16* __restrict__ ts,
    const __bf16* __restrict__ WcT, const float* __restrict__ clsb,
    float* __restrict__ out)
{
  int r0 = blockIdx.x * 16;
  int tid = threadIdx.x;
  int w = tid >> 6, lid = tid & 63;
  int frow = lid & 15, kg = lid >> 4;
  int row = r0 + frow;
  long hsrow = (long)row * EMB_;
  floatx4 acc[7] = {};
  int kbase0 = w*1536;
  for (int s = 0; s < 48; ++s) {
    int kb = kbase0 + s*32 + kg*8;
    int q16 = (kb >> 8) << 4;
    int ii = (kb >> 4) & 15;
    int jj0 = kb & 15;
    float hv = (float)hs[hsrow + q16 + ii];
    V16 tsv; tsv.q = *reinterpret_cast<const uint4*>(ts + hsrow + q16 + jj0);
    bf16x8 af;
#pragma unroll
    for (int j = 0; j < 8; ++j) af[j] = (__bf16)(hv * (float)tsv.b[j]);
#pragma unroll
    for (int f = 0; f < 7; ++f) {
      V16 bv; bv.q = *reinterpret_cast<const uint4*>(WcT + (long)(f*16 + frow)*(EMB_*BS_) + kb);
      acc[f] = __builtin_amdgcn_mfma_f32_16x16x32_bf16(af, bv.v, acc[f], 0, 0, 0);
    }
  }
  __shared__ float red[8][16][112];
#pragma unroll
  for (int f = 0; f < 7; ++f)
#pragma unroll
    for (int r = 0; r < 4; ++r)
      red[w][kg*4 + r][f*16 + frow] = acc[f][r];
  __syncthreads();
  for (int e = tid; e < 16*112; e += 512) {
    int rr = e / 112, cc = e % 112;
    if (cc < NC_) {
      float s = clsb[cc];
#pragma unroll
      for (int ww = 0; ww < 8; ++ww) s += red[ww][rr][cc];
      out[(long)(r0 + rr)*NC_ + cc] = s;
    }
  }
}

extern "C" void kernel_launch(void* const* d_in, const int* in_sizes, int n_in,
                              void* d_out, int out_size, void* d_ws, size_t ws_size,
                              hipStream_t stream) {
  const float* seq   = (const float*)d_in[0];
  const float* att   = (const float*)d_in[1];
  const float* headW = (const float*)d_in[2];
  const float* headb = (const float*)d_in[3];
  const float* tailW = (const float*)d_in[4];
  const float* tailb = (const float*)d_in[5];
  const float* projW = (const float*)d_in[6];
  const float* clsW  = (const float*)d_in[7];
  const float* clsb  = (const float*)d_in[8];
  const float* mmask = (const float*)d_in[9];
  const int* midx = (const int*)d_in[10];
  const int* hts  = (const int*)d_in[11];

  char* p = (char*)d_ws;
  auto alloc_f = [&](size_t n){ float* r = (float*)p; p += n*sizeof(float); return r; };
  auto alloc_b = [&](size_t n){ __bf16* r = (__bf16*)p; p += n*2; return r; };
  float* hpre    = alloc_f((size_t)B_*NE_*EMB_);
  float* tpre    = alloc_f((size_t)B_*NE_*EMB_);
  __bf16* e_embB = alloc_b((size_t)128*H_);
  __bf16* e_att  = alloc_b((size_t)B_*NE_*NH_*L_);
  __bf16* htattb = alloc_b((size_t)2464*L_);
  __bf16* seqT   = alloc_b((size_t)B_*H_*L_);
  __bf16* rsb    = alloc_b((size_t)2432*H_);
  __bf16* Wt     = alloc_b((size_t)2*H_*2*H_);
  __bf16* clsA   = alloc_b((size_t)128*H_);
  __bf16* WcT    = alloc_b((size_t)128*EMB_*BS_);
  __bf16* projWT = alloc_b((size_t)EMB_*BS_*H_);
  // hs/ts alias projWT (projWT dead after k_mid's wc branch)
  __bf16* hsb = projWT;
  __bf16* tsb = projWT + (size_t)B_*P_*EMB_;

  k_prep<<<S1_CVT + S1_TPW + S1_TPS + S1_POOL + S1_ATT, 256, 0, stream>>>(
      seq, att, headW, tailW, projW, clsW, mmask, midx,
      Wt, clsA, projWT, seqT, e_embB, e_att);
  k_mid<<<S2_WC + S2_HT + S2_PRE, 256, 0, stream>>>(
      clsA, projWT, e_att, hts, e_embB, Wt, WcT, htattb, hpre, tpre);
  k_rs_mfma<<<dim3(H_/64, 10, B_), 256, 0, stream>>>(htattb, seqT, rsb);
  k_extract_mfma<<<dim3(EMB_/64, 38, 2), 256, 0, stream>>>(
      rsb, Wt, headb, tailb, hpre, tpre, hts, hsb, tsb);
  k_logits_mfma<<<150, 512, 0, stream>>>(hsb, tsb, WcT, clsb, (float*)d_out);
}